// Round 5
// baseline (684.513 us; speedup 1.0000x reference)
//
#include <hip/hip_runtime.h>

// EntNet: B=32, S=256, L=64, D=100, M=20
// K1 encode_k : one row/block contiguous streaming -> LDS stage -> column reduce
// K0 prep_k   : T[d][e] = W[e][d] / keys
// K2 project_k: sWp = enc·W^T, kg = enc·keys^T via T
// K3 entnet_scan: TWO chains (b,mA),(b,mB=mA+10) per 128-thread block.
//    Thread tid owns element e=tid for BOTH chains; shared U row = 100 VGPR
//    (round-2 lesson: 2 rows/lane = 200 VGPR spills to AGPR and dies).
//    The ~1900-cycle/step broadcast round-trip latency (invariant across
//    rounds 0/1/3) is amortized over 2 chains: added issue (+25 ds_read,
//    +50 pk_fma, +4 DPP trees) hides in the existing stall cycles.
//    One __syncthreads per step; nsv/nsw loads shared (same b).
// (Round 4 was an infra failure — container acquisition; identical rerun.)

typedef float v2f __attribute__((ext_vector_type(2)));

__global__ __launch_bounds__(320) void encode_k(
    const float* __restrict__ batch,
    const float* __restrict__ encm,
    float* __restrict__ enc)
{
    __shared__ float prod[6400];
    __shared__ float part[200];
    const int t = threadIdx.x;
    const int row = blockIdx.x;       // 8192 blocks
    const float4* rb = (const float4*)batch + (size_t)row * 1600;
    const float4* e4 = (const float4*)encm;
    float4* p4 = (float4*)prod;
    #pragma unroll
    for (int i = 0; i < 5; ++i) {
        const int idx = i * 320 + t;
        float4 x = rb[idx];
        float4 mu = e4[idx];
        float4 p;
        p.x = x.x * mu.x; p.y = x.y * mu.y; p.z = x.z * mu.z; p.w = x.w * mu.w;
        p4[idx] = p;
    }
    __syncthreads();
    if (t < 200) {
        const int c = (t < 100) ? t : (t - 100);
        const int l0 = (t < 100) ? 0 : 32;
        float s0 = 0.f, s1 = 0.f;
        #pragma unroll
        for (int l = 0; l < 32; l += 2) {
            s0 += prod[(l0 + l) * 100 + c];
            s1 += prod[(l0 + l + 1) * 100 + c];
        }
        part[t] = s0 + s1;
    }
    __syncthreads();
    if (t < 100) enc[(size_t)row * 100 + t] = part[t] + part[100 + t];
}

__global__ void prep_k(const float* __restrict__ W,
                       const float* __restrict__ keys,
                       float* __restrict__ T)
{
    const int d = blockIdx.x;
    const int e = threadIdx.x;
    float v = 0.f;
    if (e < 100) v = W[e * 100 + d];
    else if (e < 120) v = keys[(e - 100) * 100 + d];
    T[d * 128 + e] = v;
}

__global__ __launch_bounds__(128) void project_k(
    const float* __restrict__ enc,
    const float* __restrict__ T,
    float* __restrict__ sWp,
    float* __restrict__ kg)
{
    __shared__ float encS[400];
    const int t = threadIdx.x;
    const int row0 = blockIdx.x * 4;
    if (t < 100) ((float4*)encS)[t] = ((const float4*)(enc + (size_t)row0 * 100))[t];
    __syncthreads();
    float a0 = 0.f, a1 = 0.f, a2 = 0.f, a3 = 0.f;
    #pragma unroll 4
    for (int d = 0; d < 100; ++d) {
        const float w = T[d * 128 + t];
        a0 += w * encS[d];
        a1 += w * encS[100 + d];
        a2 += w * encS[200 + d];
        a3 += w * encS[300 + d];
    }
    if (t < 100) {
        sWp[(size_t)row0 * 100 + t]       = a0;
        sWp[(size_t)(row0 + 1) * 100 + t] = a1;
        sWp[(size_t)(row0 + 2) * 100 + t] = a2;
        sWp[(size_t)(row0 + 3) * 100 + t] = a3;
    } else if (t < 120) {
        const int m = t - 100;
        kg[(size_t)row0 * 20 + m]       = a0;
        kg[(size_t)(row0 + 1) * 20 + m] = a1;
        kg[(size_t)(row0 + 2) * 20 + m] = a2;
        kg[(size_t)(row0 + 3) * 20 + m] = a3;
    }
}

template <int CTRL>
__device__ __forceinline__ float dpp_add_f(float x) {
    int s = __builtin_amdgcn_update_dpp(0, __float_as_int(x), CTRL, 0xF, 0xF, true);
    return x + __int_as_float(s);
}
#define DPP6(v) v = dpp_add_f<0x111>(v); v = dpp_add_f<0x112>(v); v = dpp_add_f<0x114>(v); \
                v = dpp_add_f<0x118>(v); v = dpp_add_f<0x142>(v); v = dpp_add_f<0x143>(v);

// Dual-chain lane-local matvec: QA = U[e,:]·candA, QB = U[e,:]·candB.
// 50 uniform ds_read_b128 broadcasts + 100 pk_fma in 8 independent chains.
#define MATVEC2(QA_, QB_, CA4, CB4)                                     \
    {                                                                   \
        v2f A0 = {0.f,0.f}, A1 = {0.f,0.f}, A2 = {0.f,0.f}, A3 = {0.f,0.f}; \
        v2f B0 = {0.f,0.f}, B1 = {0.f,0.f}, B2 = {0.f,0.f}, B3 = {0.f,0.f}; \
        _Pragma("unroll")                                               \
        for (int j = 0; j < 25; ++j) {                                  \
            float4 ca = (CA4)[j];                                       \
            float4 cb = (CB4)[j];                                       \
            v2f alo = {ca.x, ca.y}, ahi = {ca.z, ca.w};                 \
            v2f blo = {cb.x, cb.y}, bhi = {cb.z, cb.w};                 \
            if (j & 1) {                                                \
                A2 = __builtin_elementwise_fma(UE[2*j],   alo, A2);     \
                A3 = __builtin_elementwise_fma(UE[2*j+1], ahi, A3);     \
                B2 = __builtin_elementwise_fma(UE[2*j],   blo, B2);     \
                B3 = __builtin_elementwise_fma(UE[2*j+1], bhi, B3);     \
            } else {                                                    \
                A0 = __builtin_elementwise_fma(UE[2*j],   alo, A0);     \
                A1 = __builtin_elementwise_fma(UE[2*j+1], ahi, A1);     \
                B0 = __builtin_elementwise_fma(UE[2*j],   blo, B0);     \
                B1 = __builtin_elementwise_fma(UE[2*j+1], bhi, B1);     \
            }                                                           \
        }                                                               \
        v2f SA = (A0 + A1) + (A2 + A3);                                 \
        v2f SB = (B0 + B1) + (B2 + B3);                                 \
        QA_ = SA.x + SA.y;                                              \
        QB_ = SB.x + SB.y;                                              \
    }

__global__ __launch_bounds__(128) void entnet_scan(
    const float* __restrict__ enc,    // [8192*100]
    const float* __restrict__ sWp,    // [8192*100]
    const float* __restrict__ kg,     // [8192*20]
    const float* __restrict__ keys,   // [20*100]
    const float* __restrict__ U,      // [100*100]
    const float* __restrict__ V,      // [100*100]
    const float* __restrict__ paPtr,
    float* __restrict__ out)          // [32*20*100]
{
    __shared__ float cbuf[2][2][128];  // [parity][chain][tid] cand broadcast
    __shared__ float4 red[2][2][2];    // [parity][chain][wave] = {q3,p4,q0,r1}
    const int tid  = threadIdx.x;
    const int lane = tid & 63;
    const int wid  = tid >> 6;
    // 320 blocks: XCD = blockIdx%8 serves b in {4*xcd..4*xcd+3}
    const int xcd = blockIdx.x & 7;
    const int gg  = blockIdx.x >> 3;          // 0..39
    const int b  = xcd * 4 + gg / 10;
    const int mA = gg % 10;
    const int mB = mA + 10;
    const bool act = (tid < 100);
    const float h = act ? 1.f : 0.f;
    const int e = act ? tid : 99;
    const float pa = paPtr[0];

    // U row e as (k,k+1) v2f pairs: 100 VGPRs, shared by both chains.
    v2f UE[50];
    {
        const float4* u = (const float4*)(U + e * 100);
        #pragma unroll
        for (int k = 0; k < 25; ++k) {
            float4 a = u[k];
            UE[2*k]   = (v2f){a.x, a.y};
            UE[2*k+1] = (v2f){a.z, a.w};
        }
    }

    // kv = V[e,:] . keys[m,:] per chain (V row loads shared)
    float kvA = 0.f, kvB = 0.f;
    {
        const float4* kmA = (const float4*)(keys + mA * 100);
        const float4* kmB = (const float4*)(keys + mB * 100);
        const float4* vv = (const float4*)(V + e * 100);
        #pragma unroll
        for (int k = 0; k < 25; ++k) {
            float4 a = vv[k], ka = kmA[k], kb = kmB[k];
            kvA += a.x * ka.x + a.y * ka.y + a.z * ka.z + a.w * ka.w;
            kvB += a.x * kb.x + a.y * kb.y + a.z * kb.z + a.w * kb.w;
        }
    }

    const float* encRow = enc + (size_t)b * 25600;
    const float* sWRow  = sWp + (size_t)b * 25600;
    const float* kgRowA = kg + (size_t)b * 5120 + mA;
    const float* kgRowB = kg + (size_t)b * 5120 + mB;

    const float k0A = keys[mA * 100 + e];
    const float k0B = keys[mB * 100 + e];
    float nmA = k0A, nmB = k0B;       // unnormalized mem; true mem = rn*nm

    // ---- init via parity-1 buffers: P = U·nm0, nsq = ||nm0||², Q1i = enc0·nm0
    cbuf[1][0][tid] = k0A;
    cbuf[1][1][tid] = k0B;
    const float sv0 = encRow[e];
    float nqA  = h * k0A * k0A;
    float nqB  = h * k0B * k0B;
    float q1iA = h * sv0 * k0A;
    float q1iB = h * sv0 * k0B;
    #define RNDI(C) nqA = dpp_add_f<C>(nqA); nqB = dpp_add_f<C>(nqB); \
                    q1iA = dpp_add_f<C>(q1iA); q1iB = dpp_add_f<C>(q1iB);
    RNDI(0x111) RNDI(0x112) RNDI(0x114) RNDI(0x118) RNDI(0x142) RNDI(0x143)
    #undef RNDI
    if (lane == 63) {
        red[1][0][wid] = (float4){nqA, q1iA, 0.f, 0.f};
        red[1][1][wid] = (float4){nqB, q1iB, 0.f, 0.f};
    }
    __syncthreads();

    float PA, PB;
    MATVEC2(PA, PB, (const float4*)&cbuf[1][0][0], (const float4*)&cbuf[1][1][0]);

    float nsqA, nsqB, gA, gB;
    {
        float4 a0 = red[1][0][0], a1 = red[1][0][1];
        float4 b0 = red[1][1][0], b1 = red[1][1][1];
        nsqA = a0.x + a1.x;
        nsqB = b0.x + b1.x;
        gA = 1.f / (1.f + __expf(-((a0.y + a1.y) + kgRowA[0])));  // rn == 1 at t=0
        gB = 1.f / (1.f + __expf(-((b0.y + b1.y) + kgRowB[0])));
    }
    float rnA = 1.f, rnB = 1.f;
    float sw = sWRow[e];

    for (int step = 0; step < 256; ++step) {
        const int nxt = (step < 255 ? step + 1 : 255);
        const float nsv = encRow[nxt * 100 + e];   // shared (per-b)
        const float nsw = sWRow[nxt * 100 + e];
        const float nkgA = kgRowA[nxt * 20];
        const float nkgB = kgRowB[nxt * 20];

        // fronts (independent): P -> x -> cand
        const float xA = rnA * PA + kvA + sw;
        const float xB = rnB * PB + kvB + sw;
        const float cA = h * ((xA >= 0.f) ? xA : pa * xA);
        const float cB = h * ((xB >= 0.f) ? xB : pa * xB);
        const int bi = step & 1;
        cbuf[bi][0][tid] = cA;
        cbuf[bi][1][tid] = cB;

        // 8 cross-lane dots BEFORE the barrier (h-masked via cA/cB)
        float q3A = nmA * cA, p4A = cA * cA, q0A = h * nsv * nmA, r1A = nsv * cA;
        float q3B = nmB * cB, p4B = cB * cB, q0B = h * nsv * nmB, r1B = nsv * cB;
        #define RND8(C) q3A = dpp_add_f<C>(q3A); p4A = dpp_add_f<C>(p4A); \
                        q0A = dpp_add_f<C>(q0A); r1A = dpp_add_f<C>(r1A); \
                        q3B = dpp_add_f<C>(q3B); p4B = dpp_add_f<C>(p4B); \
                        q0B = dpp_add_f<C>(q0B); r1B = dpp_add_f<C>(r1B);
        RND8(0x111) RND8(0x112) RND8(0x114) RND8(0x118) RND8(0x142) RND8(0x143)
        #undef RND8
        if (lane == 63) {
            red[bi][0][wid] = (float4){q3A, p4A, q0A, r1A};
            red[bi][1][wid] = (float4){q3B, p4B, q0B, r1B};
        }
        __syncthreads();

        // dual matvec: 50 uniform ds_read_b128 + 100 pk_fma
        float QA, QB;
        MATVEC2(QA, QB, (const float4*)&cbuf[bi][0][0], (const float4*)&cbuf[bi][1][0]);

        float4 ra0 = red[bi][0][0], ra1 = red[bi][0][1];
        float4 rb0 = red[bi][1][0], rb1 = red[bi][1][1];
        const float Q3A = ra0.x + ra1.x, P4A = ra0.y + ra1.y;
        const float Q0A = ra0.z + ra1.z, R1A = ra0.w + ra1.w;
        const float Q3B = rb0.x + rb1.x, P4B = rb0.y + rb1.y;
        const float Q0B = rb0.z + rb1.z, R1B = rb0.w + rb1.w;

        const float n2A = nsqA + 2.f * (gA * rnA) * Q3A + gA * gA * P4A;
        const float n2B = nsqB + 2.f * (gB * rnB) * Q3B + gB * gB * P4B;
        const float rnnA = rsqrtf(n2A);
        const float rnnB = rsqrtf(n2B);
        nsqA = 1.f; nsqB = 1.f;

        nmA = rnA * nmA + gA * cA;
        nmB = rnB * nmB + gB * cB;
        PA  = rnA * PA  + gA * QA;
        PB  = rnB * PB  + gB * QB;

        // gates for t+1: nsv·nm' = rn*(nsv·nm) + g*(nsv·cand)
        const float Q1A = rnA * Q0A + gA * R1A;
        const float Q1B = rnB * Q0B + gB * R1B;
        gA = 1.f / (1.f + __expf(-(rnnA * Q1A + nkgA)));
        gB = 1.f / (1.f + __expf(-(rnnB * Q1B + nkgB)));

        rnA = rnnA; rnB = rnnB;
        sw = nsw;
    }
    if (act) {
        out[(size_t)(b * 20 + mA) * 100 + tid] = nmA * rnA;
        out[(size_t)(b * 20 + mB) * 100 + tid] = nmB * rnB;
    }
}

extern "C" void kernel_launch(void* const* d_in, const int* in_sizes, int n_in,
                              void* d_out, int out_size, void* d_ws, size_t ws_size,
                              hipStream_t stream) {
    const float* batch = (const float*)d_in[0];
    const float* encm  = (const float*)d_in[1];
    const float* keys  = (const float*)d_in[2];
    const float* U     = (const float*)d_in[3];
    const float* V     = (const float*)d_in[4];
    const float* W     = (const float*)d_in[5];
    const float* pa    = (const float*)d_in[6];
    float* out = (float*)d_out;

    float* enc = (float*)d_ws;          // 819200 floats
    float* sWp = enc + 819200;          // 819200 floats
    float* kgb = sWp + 819200;          // 163840 floats
    float* T   = kgb + 163840;          // 12800 floats

    encode_k<<<8192, 320, 0, stream>>>(batch, encm, enc);
    prep_k<<<100, 128, 0, stream>>>(W, keys, T);
    project_k<<<2048, 128, 0, stream>>>(enc, T, sWp, kgb);
    entnet_scan<<<320, 128, 0, stream>>>(enc, sWp, kgb, keys, U, V, pa, out);
}

// Round 6
// 487.888 us; speedup vs baseline: 1.4030x; 1.4030x over previous
//
#include <hip/hip_runtime.h>

// EntNet: B=32, S=256, L=64, D=100, M=20
// K1 encode_k : one row/block contiguous streaming -> LDS stage -> column reduce
// K0 prep_k   : T[d][e] = W[e][d] / keys
// K2 project_k: sWp = enc·W^T, kg = enc·keys^T via T
// K3 entnet_scan: 640 chains, 1 wave, LDS cand broadcast + v_pk_fma matvec.
//    KEY FIX (r6): rounds 0-5 all had VGPR_Count (108-140) far below the
//    declared U-register footprint (100-200 floats) => the compiler was
//    rematerializing U as in-loop cache reloads, adding ~1200 stall
//    cycles/step (the invariant "1900-cycle floor"). Pin every UE element
//    via empty asm "+v" so remat is impossible; waves_per_eu(1,1) gives the
//    512-VGPR budget to hold them.

typedef float v2f __attribute__((ext_vector_type(2)));

__global__ __launch_bounds__(320) void encode_k(
    const float* __restrict__ batch,
    const float* __restrict__ encm,
    float* __restrict__ enc)
{
    __shared__ float prod[6400];
    __shared__ float part[200];
    const int t = threadIdx.x;
    const int row = blockIdx.x;       // 8192 blocks
    const float4* rb = (const float4*)batch + (size_t)row * 1600;
    const float4* e4 = (const float4*)encm;
    float4* p4 = (float4*)prod;
    #pragma unroll
    for (int i = 0; i < 5; ++i) {
        const int idx = i * 320 + t;
        float4 x = rb[idx];
        float4 mu = e4[idx];
        float4 p;
        p.x = x.x * mu.x; p.y = x.y * mu.y; p.z = x.z * mu.z; p.w = x.w * mu.w;
        p4[idx] = p;
    }
    __syncthreads();
    if (t < 200) {
        const int c = (t < 100) ? t : (t - 100);
        const int l0 = (t < 100) ? 0 : 32;
        float s0 = 0.f, s1 = 0.f;
        #pragma unroll
        for (int l = 0; l < 32; l += 2) {
            s0 += prod[(l0 + l) * 100 + c];
            s1 += prod[(l0 + l + 1) * 100 + c];
        }
        part[t] = s0 + s1;
    }
    __syncthreads();
    if (t < 100) enc[(size_t)row * 100 + t] = part[t] + part[100 + t];
}

__global__ void prep_k(const float* __restrict__ W,
                       const float* __restrict__ keys,
                       float* __restrict__ T)
{
    const int d = blockIdx.x;
    const int e = threadIdx.x;
    float v = 0.f;
    if (e < 100) v = W[e * 100 + d];
    else if (e < 120) v = keys[(e - 100) * 100 + d];
    T[d * 128 + e] = v;
}

__global__ __launch_bounds__(128) void project_k(
    const float* __restrict__ enc,
    const float* __restrict__ T,
    float* __restrict__ sWp,
    float* __restrict__ kg)
{
    __shared__ float encS[400];
    const int t = threadIdx.x;
    const int row0 = blockIdx.x * 4;
    if (t < 100) ((float4*)encS)[t] = ((const float4*)(enc + (size_t)row0 * 100))[t];
    __syncthreads();
    float a0 = 0.f, a1 = 0.f, a2 = 0.f, a3 = 0.f;
    #pragma unroll 4
    for (int d = 0; d < 100; ++d) {
        const float w = T[d * 128 + t];
        a0 += w * encS[d];
        a1 += w * encS[100 + d];
        a2 += w * encS[200 + d];
        a3 += w * encS[300 + d];
    }
    if (t < 100) {
        sWp[(size_t)row0 * 100 + t]       = a0;
        sWp[(size_t)(row0 + 1) * 100 + t] = a1;
        sWp[(size_t)(row0 + 2) * 100 + t] = a2;
        sWp[(size_t)(row0 + 3) * 100 + t] = a3;
    } else if (t < 120) {
        const int m = t - 100;
        kg[(size_t)row0 * 20 + m]       = a0;
        kg[(size_t)(row0 + 1) * 20 + m] = a1;
        kg[(size_t)(row0 + 2) * 20 + m] = a2;
        kg[(size_t)(row0 + 3) * 20 + m] = a3;
    }
}

template <int CTRL>
__device__ __forceinline__ float dpp_add_f(float x) {
    int s = __builtin_amdgcn_update_dpp(0, __float_as_int(x), CTRL, 0xF, 0xF, true);
    return x + __int_as_float(s);
}
__device__ __forceinline__ float lane63(float x) {
    return __int_as_float(__builtin_amdgcn_readlane(__float_as_int(x), 63));
}
#define DPP6(v) v = dpp_add_f<0x111>(v); v = dpp_add_f<0x112>(v); v = dpp_add_f<0x114>(v); \
                v = dpp_add_f<0x118>(v); v = dpp_add_f<0x142>(v); v = dpp_add_f<0x143>(v);

// Store cand to LDS: lane -> cbuf[lane] (k=0..63), cbuf[64+lane] (k=64..99;
// lanes 36..63 write the 100..127 pad, never read).
#define CAND_STORE(C0, C1) { cbuf[lane] = (C0); cbuf[64 + lane] = (C1); }

// RES(v2f) = U[e0/e1,:] . cand. 25 uniform ds_read_b128 broadcasts + 100
// v_pk_fma_f32 (natural (k,k+1) pairing: no splat, no op_sel needed).
#define MATVEC_READ(RES)                                                \
    {                                                                   \
        v2f A0 = {0.f, 0.f}, A1 = {0.f, 0.f};                           \
        v2f A2 = {0.f, 0.f}, A3 = {0.f, 0.f};                           \
        _Pragma("unroll")                                               \
        for (int j = 0; j < 25; ++j) {                                  \
            float4 cc = cbuf4[j];                                       \
            v2f clo = {cc.x, cc.y};                                     \
            v2f chi = {cc.z, cc.w};                                     \
            A0 = __builtin_elementwise_fma(UE0[2 * j],     clo, A0);    \
            A1 = __builtin_elementwise_fma(UE0[2 * j + 1], chi, A1);    \
            A2 = __builtin_elementwise_fma(UE1[2 * j],     clo, A2);    \
            A3 = __builtin_elementwise_fma(UE1[2 * j + 1], chi, A3);    \
        }                                                               \
        v2f sA = A0 + A1, sB = A2 + A3;                                 \
        RES.x = sA.x + sA.y;                                            \
        RES.y = sB.x + sB.y;                                            \
    }

__global__ __attribute__((amdgpu_waves_per_eu(1, 1))) __launch_bounds__(64)
void entnet_scan(
    const float* __restrict__ enc,    // [8192*100]
    const float* __restrict__ sWp,    // [8192*100]
    const float* __restrict__ kg,     // [8192*20]
    const float* __restrict__ keys,   // [20*100]
    const float* __restrict__ U,      // [100*100]
    const float* __restrict__ V,      // [100*100]
    const float* __restrict__ paPtr,
    float* __restrict__ out)          // [32*20*100]
{
    __shared__ float4 cbuf4[32];      // 128 floats: cand broadcast buffer
    float* cbuf = (float*)cbuf4;
    const int lane = threadIdx.x;
    // XCD swizzle: XCD = blockIdx%8 serves b in {4*xcd .. 4*xcd+3}
    const int xcd = blockIdx.x & 7;
    const int gg  = blockIdx.x >> 3;          // 0..79
    const int b = xcd * 4 + gg / 20;
    const int m = gg % 20;
    const bool hi = (lane < 36);
    const float h = hi ? 1.f : 0.f;
    const int e0 = lane;
    const int e1 = hi ? (64 + lane) : 99;
    const float pa = paPtr[0];

    // U rows e0/e1 as (k,k+1) v2f pairs: UE0[j] = {U[e0][2j], U[e0][2j+1]}
    v2f UE0[50], UE1[50];
    {
        const float4* u0 = (const float4*)(U + e0 * 100);
        const float4* u1 = (const float4*)(U + e1 * 100);
        #pragma unroll
        for (int k = 0; k < 25; ++k) {
            float4 a = u0[k], c = u1[k];
            UE0[2 * k]     = (v2f){a.x, a.y};
            UE0[2 * k + 1] = (v2f){a.z, a.w};
            UE1[2 * k]     = (v2f){c.x, c.y};
            UE1[2 * k + 1] = (v2f){c.z, c.w};
        }
    }
    // PIN: route every UE element through an empty asm so the compiler cannot
    // rematerialize it as an in-loop reload (the r0-r5 ~1200 cyc/step stall).
    // asm result is opaque -> must stay register-resident (512-VGPR budget).
    #pragma unroll
    for (int k = 0; k < 50; ++k) {
        asm("" : "+v"(UE0[k]));
        asm("" : "+v"(UE1[k]));
    }

    float kv0 = 0.f, kv1 = 0.f;
    {
        const float4* km = (const float4*)(keys + m * 100);
        const float4* v0 = (const float4*)(V + e0 * 100);
        const float4* v1 = (const float4*)(V + e1 * 100);
        #pragma unroll
        for (int k = 0; k < 25; ++k) {
            float4 kk = km[k], a = v0[k], c = v1[k];
            kv0 += a.x * kk.x + a.y * kk.y + a.z * kk.z + a.w * kk.w;
            kv1 += c.x * kk.x + c.y * kk.y + c.z * kk.z + c.w * kk.w;
        }
    }
    const float k0 = keys[m * 100 + e0];
    const float k1 = h * keys[m * 100 + e1];
    float nm0 = k0, nm1 = k1;        // unnormalized mem; true mem = rn*nm

    v2f P;                            // P = U . nm (register recurrence)
    CAND_STORE(k0, k1);
    MATVEC_READ(P);

    float nq = k0 * k0 + k1 * k1;     // ||mem_0||^2
    DPP6(nq)
    float nsq = lane63(nq);
    float rn = 1.f;

    const float* encRow = enc + (size_t)b * 25600;
    const float* sWRow  = sWp + (size_t)b * 25600;
    const float* kgRow  = kg + (size_t)b * 5120 + m;

    float sw0 = sWRow[e0], sw1 = sWRow[e1];
    float g;
    {
        const float sv0 = encRow[e0], sv1 = encRow[e1];
        const float kg0 = kgRow[0];
        float q1 = sv0 * nm0 + sv1 * nm1;
        DPP6(q1)
        const float Q1 = lane63(q1);
        g = 1.f / (1.f + __expf(-(Q1 + kg0)));   // rn == 1 at t=0
    }

    for (int step = 0; step < 256; ++step) {
        const int nxt = (step < 255 ? step + 1 : 255);
        const float nsv0 = encRow[nxt * 100 + e0], nsv1 = encRow[nxt * 100 + e1];
        const float nsw0 = sWRow[nxt * 100 + e0], nsw1 = sWRow[nxt * 100 + e1];
        const float nkg  = kgRow[nxt * 20];

        // critical path: P -> x -> cand -> LDS round-trip matvec -> P'
        const float x0 = rn * P.x + kv0 + sw0;
        const float x1 = rn * P.y + kv1 + sw1;
        float c0 = (x0 >= 0.f) ? x0 : pa * x0;
        float c1 = (x1 >= 0.f) ? x1 : pa * x1;
        c1 *= h;

        CAND_STORE(c0, c1);           // issue early: LDS latency hides under DPP

        // off-path norm partials (overlap LDS round-trip)
        float q3 = nm0 * c0 + nm1 * c1;             // nm . cand
        float p4 = c0 * c0 + c1 * c1;               // cand . cand
        #define RND2(C) q3 = dpp_add_f<C>(q3); p4 = dpp_add_f<C>(p4);
        RND2(0x111) RND2(0x112) RND2(0x114) RND2(0x118) RND2(0x142) RND2(0x143)
        #undef RND2

        v2f Q;
        MATVEC_READ(Q);

        const float Q3 = lane63(q3);
        const float P4 = lane63(p4);
        const float n2 = nsq + 2.f * (g * rn) * Q3 + g * g * P4;
        const float rnn = rsqrtf(n2);               // rn_{t+1}
        nsq = 1.f;

        nm0 = rn * nm0 + g * c0;
        nm1 = rn * nm1 + g * c1;
        P.x = rn * P.x + g * Q.x;
        P.y = rn * P.y + g * Q.y;

        // gate for step t+1 (overlaps next iteration's front)
        float q1 = nsv0 * nm0 + nsv1 * nm1;
        DPP6(q1)
        const float Q1 = lane63(q1);
        g = 1.f / (1.f + __expf(-(rnn * Q1 + nkg)));

        rn = rnn;
        sw0 = nsw0; sw1 = nsw1;
    }
    float* orow = out + (size_t)(b * 20 + m) * 100;
    orow[e0] = nm0 * rn;
    if (hi) orow[e1] = nm1 * rn;
}

extern "C" void kernel_launch(void* const* d_in, const int* in_sizes, int n_in,
                              void* d_out, int out_size, void* d_ws, size_t ws_size,
                              hipStream_t stream) {
    const float* batch = (const float*)d_in[0];
    const float* encm  = (const float*)d_in[1];
    const float* keys  = (const float*)d_in[2];
    const float* U     = (const float*)d_in[3];
    const float* V     = (const float*)d_in[4];
    const float* W     = (const float*)d_in[5];
    const float* pa    = (const float*)d_in[6];
    float* out = (float*)d_out;

    float* enc = (float*)d_ws;          // 819200 floats
    float* sWp = enc + 819200;          // 819200 floats
    float* kgb = sWp + 819200;          // 163840 floats
    float* T   = kgb + 163840;          // 12800 floats

    encode_k<<<8192, 320, 0, stream>>>(batch, encm, enc);
    prep_k<<<100, 128, 0, stream>>>(W, keys, T);
    project_k<<<2048, 128, 0, stream>>>(enc, T, sWp, kgb);
    entnet_scan<<<640, 64, 0, stream>>>(enc, sWp, kgb, keys, U, V, pa, out);
}